// Round 2
// baseline (197.853 us; speedup 1.0000x reference)
//
#include <hip/hip_runtime.h>

// Problem constants
#define NXC 128
#define NYC 128
#define NZC 4
#define BC  8
#define TC  10

// idx = (((b*T + t)*NZ + z)*NX + x)*NY + y
// y stride = 1, x stride = 128, z stride = 16384, t stride = 65536, b stride = 655360
#define TSTRIDE 65536           // NZ*NX*NY
#define NTOT    5242880         // B*T*NZ*NX*NY

__global__ __launch_bounds__(256) void blackoil_kernel(
    const float* __restrict__ pressure,
    const float* __restrict__ perm,
    const float* __restrict__ Q,
    const float* __restrict__ Qw,
    const float* __restrict__ Time_,
    const float* __restrict__ Phi,
    const float* __restrict__ Swini,
    const float* __restrict__ wsat,
    float* __restrict__ out)
{
    int idx = blockIdx.x * blockDim.x + threadIdx.x;
    if (idx >= NTOT) return;

    const int y = idx & (NYC - 1);
    const int x = (idx >> 7) & (NXC - 1);
    const int t = (idx >> 16) % TC;          // idx >> 16 == b*T + t

    // neighbor offsets with edge-replicate clamping (pad-edge == clamp index)
    const int xm = (x > 0)       ? -NYC : 0;
    const int xp = (x < NXC - 1) ?  NYC : 0;
    const int ym = (y > 0)       ? -1   : 0;
    const int yp = (y < NYC - 1) ?  1   : 0;

    // ---- pressure derivatives (u = pressure * 1000) ----
    const float uc  = pressure[idx]      * 1000.0f;
    const float uxm = pressure[idx + xm] * 1000.0f;
    const float uxp = pressure[idx + xp] * 1000.0f;
    const float uym = pressure[idx + ym] * 1000.0f;
    const float uyp = pressure[idx + yp] * 1000.0f;

    const float dudx   = (uxp - uxm) * 64.0f;                 // * 0.5/h, h = 1/128
    const float dudy   = (uyp - uym) * 64.0f;
    const float dduddx = (uxp - 2.0f * uc + uxm) * 16384.0f;  // * 1/h^2
    const float dduddy = (uyp - 2.0f * uc + uym) * 16384.0f;

    // ---- mobility constants from siniuse (scalar Swini[0,0,0,0,0]) ----
    const float sini = Swini[0];
    const float S0   = (sini - 0.1f) * 1.25f;    // /(1-SWI-SWR) = /0.8
    const float cw   = S0 * S0;                  // Mw at t=0 (spatially const; /(UW*BW)=1)
    const float ct   = cw + (1.0f - S0) * (1.0f - S0) * (1.0f / 2.75f); // + Mo

    // ---- perm t=0 slice derivatives ----
    // a = m*perm + (AAY - m*LUB); m = 450/0.9 = 500, offset = 50 - 500*0.1 = 0 -> a = 500*perm
    // a1[:, :1] = ct * 500 * perm[:, :1]; a1water[:, :1] = cw * 500 * perm[:, :1]
    const int i0 = idx - t * TSTRIDE;            // same (b, z, x, y) at t = 0
    const float dpx = (perm[i0 + xp] - perm[i0 + xm]) * (500.0f * 64.0f);
    const float dpy = (perm[i0 + yp] - perm[i0 + ym]) * (500.0f * 64.0f);
    const float dcdx = ct * dpx, dcdy = ct * dpy;
    const float dadx = cw * dpx, dady = cw * dpy;

    // ---- time-varying mobility (uses prior-timestep saturation) ----
    const float a     = 500.0f * perm[idx];
    const float sat   = wsat[idx];
    const float prior = (t == 0) ? sini : wsat[idx - TSTRIDE];
    const float dsw   = fmaxf(sat - prior, 0.001f);

    const float S  = (prior - 0.1f) * 1.25f;
    const float Mw = S * S;
    const float Mo = (1.0f - S) * (1.0f - S) * (1.0f / 2.75f);
    const float a1  = (Mw + Mo) * a;
    const float a1w = Mw * a;

    // ---- sources & misc ----
    const float fin  = Q[idx]     * 5000.0f;
    const float finw = Qw[idx]    * 5000.0f;
    const float dta  = Time_[idx] * 6000.0f;
    const float phi  = Phi[idx];

    const float scale = 7.8125e-8f;  // dxf * 1e-5 = 1e-5/128

    const float p_loss = scale * (fin + dcdx * dudx + a1 * dduddx
                                      + dcdy * dudy + a1 * dduddy);
    const float flux   = dadx * dudx + a1w * dduddx + dady * dudy + a1w * dduddy;
    const float s_loss = scale * (phi * (dsw / dta) - (flux + finw));

    out[idx]        = p_loss;
    out[idx + NTOT] = s_loss;
}

extern "C" void kernel_launch(void* const* d_in, const int* in_sizes, int n_in,
                              void* d_out, int out_size, void* d_ws, size_t ws_size,
                              hipStream_t stream) {
    const float* pressure = (const float*)d_in[0];
    const float* perm     = (const float*)d_in[1];
    const float* Q        = (const float*)d_in[2];
    const float* Qw       = (const float*)d_in[3];
    const float* Time_    = (const float*)d_in[4];
    // d_in[5] = Pini (unused by the reference)
    const float* Phi      = (const float*)d_in[6];
    const float* Swini    = (const float*)d_in[7];
    const float* wsat     = (const float*)d_in[8];
    float* out = (float*)d_out;

    const int threads = 256;
    const int blocks  = (NTOT + threads - 1) / threads;   // 20480
    blackoil_kernel<<<blocks, threads, 0, stream>>>(
        pressure, perm, Q, Qw, Time_, Phi, Swini, wsat, out);
}